// Round 2
// baseline (117.019 us; speedup 1.0000x reference)
//
#include <hip/hip_runtime.h>
#include <hip/hip_fp16.h>

typedef _Float16 h8 __attribute__((ext_vector_type(8)));
typedef _Float16 h4 __attribute__((ext_vector_type(4)));
typedef float f32x4 __attribute__((ext_vector_type(4)));

#define MFMA16(a, b, c) __builtin_amdgcn_mfma_f32_16x16x32_f16((a), (b), (c), 0, 0, 0)

static constexpr int MM = 2048, NN = 2048, DD = 128;
static constexpr int MT = 64, KT = 64, NT = NN / KT;  // 32 key tiles

static constexpr float C1 = 0.25503487f;              // 2*log2(e)/sqrt(128)
static constexpr float C2 = 28.853900817779268f;      // 20*log2(e)
static constexpr float CVALID = 14.426950408889634f;  // 10*log2(e)
static constexpr float CMASK = -1.0e30f;

// ---------------- mask -> per-key bias constant (exp2 domain) ----------------
// Detects on-device whether the bool mask arrived as u8, i32, or f32.
// Scans exactly 32768 bytes = min possible buffer size (u8 case) -> safe.
__global__ __launch_bounds__(256) void prep_bias(const void* __restrict__ mraw,
                                                 float* __restrict__ biasC) {
  const int tid = threadIdx.x;
  const unsigned int* mw = (const unsigned int*)mraw;
  const unsigned char* mb = (const unsigned char*)mraw;
  int okW = 1;  // word-typed (i32 0/1 or f32 0.0/1.0)
  for (int w = tid; w < 8192; w += 256) {
    unsigned int v = mw[w];
    okW &= (v == 0u || v == 1u || v == 0x3f800000u) ? 1 : 0;
  }
  __shared__ int sW;
  if (tid == 0) sW = 1;
  __syncthreads();
  if (!okW) atomicAnd(&sW, 0);
  __syncthreads();
  const int i = blockIdx.x * 256 + tid;  // grid covers 32768
  bool masked = sW ? (mw[i] != 0u) : (mb[i] != 0);
  biasC[i] = masked ? CMASK : CVALID;
}

// ---------------- fused attention ----------------
// Block: 256 thr = 4 waves over (2 row-halves x 2 key-halves) of a 64-row tile.
// Wave: 32 query rows x 32 keys per K-tile. Q split fp16 hi/lo in registers
// (2-term MFMA for fp32-grade logits); K fp16 in LDS (XOR swizzle (key&7)<<4
// applied to the intra-row offset on BOTH write and read); V transposed
// [d][key] fp16 in LDS (swizzle ((d>>1)&7)<<4). No softmax max needed:
// logits clipped to +-10. p = exp2(Ccol - C2*rcp(exp2(s*C1)+1)).
__global__ __launch_bounds__(256, 2) void attn_main(
    const float* __restrict__ Qg, const float* __restrict__ Kg,
    const float* __restrict__ Vg, const float* __restrict__ biasC,
    float* __restrict__ out) {
  __shared__ __align__(16) unsigned char smem[43264];
  // [0,16384)      K tile  fp16 [64 keys][128 d], swizzled
  // [16384,32768)  V^T     fp16 [128 d][64 keys], swizzled
  // [32768,43008)  per-wave P [32 rows][40 f16] (pad: stride 80B = 5*16B)
  // [43008,43264)  rowsum exchange (64 f32)
  // epilogue: [0,32768) reused for partial-O exchange
  const int tid = threadIdx.x;
  const int lane = tid & 63;
  const int wv = tid >> 6;
  const int r = lane & 15;   // A-row / D-col index
  const int g = lane >> 4;   // k-octet index
  const int rw = wv >> 1;    // row half
  const int h = wv & 1;      // key half
  const int b = blockIdx.x >> 5;
  const int mt = blockIdx.x & 31;
  const int m0 = mt * MT + rw * 32;

  // ---- Q fragments, fp16 hi/lo (registers, reused for all 32 K-tiles) ----
  h8 qh[2][4], ql[2][4];
  {
    const float* qb = Qg + ((size_t)b * MM + m0) * DD;
#pragma unroll
    for (int rf = 0; rf < 2; ++rf) {
      const float* qr = qb + (16 * rf + r) * DD;
#pragma unroll
      for (int t = 0; t < 4; ++t) {
        f32x4 a = *(const f32x4*)(qr + 32 * t + 8 * g);
        f32x4 c = *(const f32x4*)(qr + 32 * t + 8 * g + 4);
        h8 hi, lo;
#pragma unroll
        for (int j = 0; j < 4; ++j) {
          _Float16 ha = (_Float16)a[j];
          _Float16 hc = (_Float16)c[j];
          hi[j] = ha;
          hi[j + 4] = hc;
          lo[j] = (_Float16)(a[j] - (float)ha);
          lo[j + 4] = (_Float16)(c[j] - (float)hc);
        }
        qh[rf][t] = hi;
        ql[rf][t] = lo;
      }
    }
  }

  f32x4 acc[2][8];
#pragma unroll
  for (int rf = 0; rf < 2; ++rf)
#pragma unroll
    for (int cd = 0; cd < 8; ++cd) acc[rf][cd] = (f32x4){0.f, 0.f, 0.f, 0.f};
  float rs[2][4] = {{0.f, 0.f, 0.f, 0.f}, {0.f, 0.f, 0.f, 0.f}};

  const float* kb = Kg + (size_t)b * NN * DD;
  const float* vbp = Vg + (size_t)b * NN * DD;
  const float* cb = biasC + b * NN;
  _Float16* plds = (_Float16*)(smem + 32768 + wv * 2560);

  for (int tn = 0; tn < NT; ++tn) {
    __syncthreads();
    // ---- stage K tile (fp16, row-swizzled) ----
    {
      const float* ks = kb + tn * KT * DD;
#pragma unroll
      for (int i = 0; i < 8; ++i) {
        const int flat = i * 1024 + tid * 4;
        const int key = flat >> 7;
        const int d0 = flat & 127;
        f32x4 v = *(const f32x4*)(ks + flat);
        h4 hv;
#pragma unroll
        for (int j = 0; j < 4; ++j) hv[j] = (_Float16)v[j];
        int byi = (key << 8) + ((d0 << 1) ^ ((key & 7) << 4));
        *(h4*)(smem + byi) = hv;
      }
      // ---- stage V^T (4x4 in-register transpose blocks) ----
      const float* vs = vbp + tn * KT * DD;
#pragma unroll
      for (int it = 0; it < 2; ++it) {
        const int id = it * 256 + tid;
        const int bk = id >> 5;   // key block (4 keys)
        const int bd = id & 31;   // d block (4 d)
        f32x4 rows[4];
#pragma unroll
        for (int q = 0; q < 4; ++q)
          rows[q] = *(const f32x4*)(vs + (4 * bk + q) * DD + 4 * bd);
#pragma unroll
        for (int p = 0; p < 4; ++p) {
          h4 w;
#pragma unroll
          for (int q = 0; q < 4; ++q) w[q] = (_Float16)rows[q][p];
          const int d = 4 * bd + p;
          int byi = (d << 7) + (((bk << 3)) ^ (((d >> 1) & 7) << 4));
          *(h4*)(smem + 16384 + byi) = w;
        }
      }
    }
    __syncthreads();

    // ---- QK^T (2-term hi/lo) + clipped-softmax transform ----
#pragma unroll
    for (int c = 0; c < 2; ++c) {
      f32x4 S0 = {0.f, 0.f, 0.f, 0.f}, S1 = {0.f, 0.f, 0.f, 0.f};
      const int key = h * 32 + 16 * c + r;
      const int krow = key << 8;
      const int ksw = (key & 7) << 4;
#pragma unroll
      for (int t = 0; t < 4; ++t) {
        h8 kf = *(const h8*)(smem + krow + ((64 * t + 16 * g) ^ ksw));
        S0 = MFMA16(qh[0][t], kf, S0);
        S0 = MFMA16(ql[0][t], kf, S0);
        S1 = MFMA16(qh[1][t], kf, S1);
        S1 = MFMA16(ql[1][t], kf, S1);
      }
      const float Cc = cb[tn * KT + key];
#pragma unroll
      for (int j = 0; j < 4; ++j) {
        float u0 = __builtin_amdgcn_exp2f(S0[j] * C1);
        float p0 = __builtin_amdgcn_exp2f(
            fmaf(-C2, __builtin_amdgcn_rcpf(u0 + 1.0f), Cc));
        rs[0][j] += p0;
        plds[(4 * g + j) * 40 + 16 * c + r] = (_Float16)p0;
        float u1 = __builtin_amdgcn_exp2f(S1[j] * C1);
        float p1 = __builtin_amdgcn_exp2f(
            fmaf(-C2, __builtin_amdgcn_rcpf(u1 + 1.0f), Cc));
        rs[1][j] += p1;
        plds[(16 + 4 * g + j) * 40 + 16 * c + r] = (_Float16)p1;
      }
    }
    // ---- P·V, accumulate into persistent C registers ----
    h8 a0 = *(const h8*)((unsigned char*)plds + r * 80 + 16 * g);
    h8 a1 = *(const h8*)((unsigned char*)plds + (16 + r) * 80 + 16 * g);
#pragma unroll
    for (int cd = 0; cd < 8; ++cd) {
      const int d = 16 * cd + r;
      int byi = (d << 7) + ((64 * h + 16 * g) ^ (((d >> 1) & 7) << 4));
      h8 vf = *(const h8*)(smem + 16384 + byi);
      acc[0][cd] = MFMA16(a0, vf, acc[0][cd]);
      acc[1][cd] = MFMA16(a1, vf, acc[1][cd]);
    }
  }

  // ---- rowsum: reduce over the 16 column-lanes ----
#pragma unroll
  for (int rf = 0; rf < 2; ++rf)
#pragma unroll
    for (int j = 0; j < 4; ++j) {
      float v = rs[rf][j];
      v += __shfl_xor(v, 1);
      v += __shfl_xor(v, 2);
      v += __shfl_xor(v, 4);
      v += __shfl_xor(v, 8);
      rs[rf][j] = v;
    }

  // ---- combine the two key-halves, normalize, store ----
  __syncthreads();
  float* olds = (float*)smem;
  float* rslds = (float*)(smem + 43008);
  if (h == 1) {
    float* my = olds + rw * 4096;
#pragma unroll
    for (int rf = 0; rf < 2; ++rf)
#pragma unroll
      for (int cd = 0; cd < 8; ++cd)
#pragma unroll
        for (int j = 0; j < 4; ++j)
          my[(16 * rf + 4 * g + j) * 128 + 16 * cd + r] = acc[rf][cd][j];
    if (r == 0) {
#pragma unroll
      for (int rf = 0; rf < 2; ++rf)
#pragma unroll
        for (int j = 0; j < 4; ++j)
          rslds[rw * 32 + 16 * rf + 4 * g + j] = rs[rf][j];
    }
  }
  __syncthreads();
  if (h == 0) {
    const float* ot = olds + rw * 4096;
    float* ob = out + ((size_t)b * MM + m0) * DD;
#pragma unroll
    for (int rf = 0; rf < 2; ++rf)
#pragma unroll
      for (int j = 0; j < 4; ++j) {
        const int rl = 16 * rf + 4 * g + j;
        const float tot = rs[rf][j] + rslds[rw * 32 + rl];
        const float inv = __builtin_amdgcn_rcpf(tot);
#pragma unroll
        for (int cd = 0; cd < 8; ++cd) {
          float v = acc[rf][cd][j] + ot[rl * 128 + 16 * cd + r];
          ob[rl * DD + 16 * cd + r] = v * inv;
        }
      }
  }
}

extern "C" void kernel_launch(void* const* d_in, const int* in_sizes, int n_in,
                              void* d_out, int out_size, void* d_ws, size_t ws_size,
                              hipStream_t stream) {
  const float* Q = (const float*)d_in[0];
  const float* K = (const float*)d_in[1];
  const float* V = (const float*)d_in[2];
  const void* mask = d_in[3];
  float* biasC = (float*)d_ws;  // 32768 floats
  float* out = (float*)d_out;
  prep_bias<<<dim3(128), dim3(256), 0, stream>>>(mask, biasC);
  attn_main<<<dim3(512), dim3(256), 0, stream>>>(Q, K, V, biasC, out);
}

// Round 3
// 94.378 us; speedup vs baseline: 1.2399x; 1.2399x over previous
//
#include <hip/hip_runtime.h>
#include <hip/hip_fp16.h>

typedef _Float16 h8 __attribute__((ext_vector_type(8)));
typedef _Float16 h4 __attribute__((ext_vector_type(4)));
typedef float f32x4 __attribute__((ext_vector_type(4)));

#define MFMA16(a, b, c) __builtin_amdgcn_mfma_f32_16x16x32_f16((a), (b), (c), 0, 0, 0)

static constexpr int MM = 2048, NN = 2048, DD = 128;
static constexpr int MT = 64, KT = 64, NT = NN / KT;  // 32 key tiles

static constexpr float C1 = 0.25503487f;              // 2*log2(e)/sqrt(128)
static constexpr float C2 = 28.853900817779268f;      // 20*log2(e)
static constexpr float CVALID = 14.426950408889634f;  // 10*log2(e)
static constexpr float CMASK = -1.0e30f;

// ---------------- mask -> per-key bias constant (exp2 domain) ----------------
__global__ __launch_bounds__(256) void prep_bias(const void* __restrict__ mraw,
                                                 float* __restrict__ biasC) {
  const int tid = threadIdx.x;
  const unsigned int* mw = (const unsigned int*)mraw;
  const unsigned char* mb = (const unsigned char*)mraw;
  int okW = 1;  // word-typed (i32 0/1 or f32 0.0/1.0)
  for (int w = tid; w < 8192; w += 256) {
    unsigned int v = mw[w];
    okW &= (v == 0u || v == 1u || v == 0x3f800000u) ? 1 : 0;
  }
  __shared__ int sW;
  if (tid == 0) sW = 1;
  __syncthreads();
  if (!okW) atomicAnd(&sW, 0);
  __syncthreads();
  const int i = blockIdx.x * 256 + tid;  // grid covers 32768
  bool masked = sW ? (mw[i] != 0u) : (mb[i] != 0);
  biasC[i] = masked ? CMASK : CVALID;
}

// ---------------- fused attention ----------------
// 4 waves over (2 row-halves x 2 key-halves) of a 64-row tile; single-fp16
// QK^T (error model: clipped-logit sigma ~2e-3, output absmax ~3e-3 < 7.2e-3).
// T14 async-stage: K/V(t+1) global loads issued into regs BEFORE compute(t);
// cvt+LDS-write after the post-compute barrier. Bias staged in LDS per block.
__global__ __launch_bounds__(256, 2) void attn_main(
    const float* __restrict__ Qg, const float* __restrict__ Kg,
    const float* __restrict__ Vg, const float* __restrict__ biasC,
    float* __restrict__ out) {
  __shared__ __align__(16) unsigned char smem[51456];
  // [0,16384)      K tile  fp16 [64 keys][128 d], swizzle (key&7)<<4 on intra
  // [16384,32768)  V^T     fp16 [128 d][64 keys], swizzle ((d>>1)&7)<<4
  // [32768,43008)  per-wave P [32 rows][40 f16] (stride 80B)
  // [43008,43264)  rowsum exchange (64 f32)
  // [43264,51456)  bias (2048 f32, whole batch)
  // epilogue: [0,32768) reused for partial-O exchange
  const int tid = threadIdx.x;
  const int lane = tid & 63;
  const int wv = tid >> 6;
  const int r = lane & 15;   // A-row / D-col index
  const int g = lane >> 4;   // k-octet index
  const int rw = wv >> 1;    // row half
  const int h = wv & 1;      // key half
  const int b = blockIdx.x >> 5;
  const int mt = blockIdx.x & 31;
  const int m0 = mt * MT + rw * 32;

  float* blds = (float*)(smem + 43264);
  {
    const float* cb = biasC + b * NN;
#pragma unroll
    for (int i = 0; i < 8; ++i) blds[tid + 256 * i] = cb[tid + 256 * i];
  }

  // ---- Q fragments fp16 (registers, reused for all 32 K-tiles) ----
  h8 qh[2][4];
  {
    const float* qb = Qg + ((size_t)b * MM + m0) * DD;
#pragma unroll
    for (int rf = 0; rf < 2; ++rf) {
      const float* qr = qb + (16 * rf + r) * DD;
#pragma unroll
      for (int t = 0; t < 4; ++t) {
        f32x4 a = *(const f32x4*)(qr + 32 * t + 8 * g);
        f32x4 c = *(const f32x4*)(qr + 32 * t + 8 * g + 4);
        h8 hi;
#pragma unroll
        for (int j = 0; j < 4; ++j) {
          hi[j] = (_Float16)a[j];
          hi[j + 4] = (_Float16)c[j];
        }
        qh[rf][t] = hi;
      }
    }
  }

  f32x4 acc[2][8];
#pragma unroll
  for (int rf = 0; rf < 2; ++rf)
#pragma unroll
    for (int cd = 0; cd < 8; ++cd) acc[rf][cd] = (f32x4){0.f, 0.f, 0.f, 0.f};
  float rs[2][4] = {{0.f, 0.f, 0.f, 0.f}, {0.f, 0.f, 0.f, 0.f}};

  const float* kb = Kg + (size_t)b * NN * DD;
  const float* vbp = Vg + (size_t)b * NN * DD;
  _Float16* plds = (_Float16*)(smem + 32768 + wv * 2560);

  // V-transpose thread mapping (fixed per thread)
  const int bk0 = tid >> 5, bd0 = tid & 31;        // it=0
  const int bk1 = (256 + tid) >> 5, bd1 = tid & 31;  // it=1

  f32x4 kpre[8], vpre[8];
  // ---- prologue: load + write tile 0 ----
#pragma unroll
  for (int i = 0; i < 8; ++i) kpre[i] = *(const f32x4*)(kb + i * 1024 + tid * 4);
#pragma unroll
  for (int q = 0; q < 4; ++q) {
    vpre[q] = *(const f32x4*)(vbp + (4 * bk0 + q) * DD + 4 * bd0);
    vpre[4 + q] = *(const f32x4*)(vbp + (4 * bk1 + q) * DD + 4 * bd1);
  }

  for (int tn = 0; tn < NT; ++tn) {
    // ---- write staged tile tn (from regs) ----
#pragma unroll
    for (int i = 0; i < 8; ++i) {
      const int flat = i * 1024 + tid * 4;
      const int key = flat >> 7;
      const int d0 = flat & 127;
      h4 hv;
#pragma unroll
      for (int j = 0; j < 4; ++j) hv[j] = (_Float16)kpre[i][j];
      *(h4*)(smem + (key << 8) + ((d0 << 1) ^ ((key & 7) << 4))) = hv;
    }
#pragma unroll
    for (int it = 0; it < 2; ++it) {
      const int bk = it ? bk1 : bk0;
      const int bd = it ? bd1 : bd0;
#pragma unroll
      for (int p = 0; p < 4; ++p) {
        h4 w;
#pragma unroll
        for (int q = 0; q < 4; ++q) w[q] = (_Float16)vpre[it * 4 + q][p];
        const int d = 4 * bd + p;
        *(h4*)(smem + 16384 + (d << 7) +
               ((bk << 3) ^ (((d >> 1) & 7) << 4))) = w;
      }
    }
    // ---- issue next tile's global loads (latency hides under compute) ----
    if (tn + 1 < NT) {
      const float* ks = kb + (tn + 1) * KT * DD;
      const float* vs = vbp + (tn + 1) * KT * DD;
#pragma unroll
      for (int i = 0; i < 8; ++i) kpre[i] = *(const f32x4*)(ks + i * 1024 + tid * 4);
#pragma unroll
      for (int q = 0; q < 4; ++q) {
        vpre[q] = *(const f32x4*)(vs + (4 * bk0 + q) * DD + 4 * bd0);
        vpre[4 + q] = *(const f32x4*)(vs + (4 * bk1 + q) * DD + 4 * bd1);
      }
    }
    __syncthreads();

    // ---- QK^T + clipped-softmax transform ----
#pragma unroll
    for (int c = 0; c < 2; ++c) {
      f32x4 S0 = {0.f, 0.f, 0.f, 0.f}, S1 = {0.f, 0.f, 0.f, 0.f};
      const int key = h * 32 + 16 * c + r;
      const int krow = key << 8;
      const int ksw = (key & 7) << 4;
      __builtin_amdgcn_s_setprio(1);
#pragma unroll
      for (int t = 0; t < 4; ++t) {
        h8 kf = *(const h8*)(smem + krow + ((64 * t + 16 * g) ^ ksw));
        S0 = MFMA16(qh[0][t], kf, S0);
        S1 = MFMA16(qh[1][t], kf, S1);
      }
      __builtin_amdgcn_s_setprio(0);
      const float Cc = blds[tn * KT + key];
#pragma unroll
      for (int j = 0; j < 4; ++j) {
        float u0 = __builtin_amdgcn_exp2f(S0[j] * C1);
        float p0 = __builtin_amdgcn_exp2f(
            fmaf(-C2, __builtin_amdgcn_rcpf(u0 + 1.0f), Cc));
        rs[0][j] += p0;
        plds[(4 * g + j) * 40 + 16 * c + r] = (_Float16)p0;
        float u1 = __builtin_amdgcn_exp2f(S1[j] * C1);
        float p1 = __builtin_amdgcn_exp2f(
            fmaf(-C2, __builtin_amdgcn_rcpf(u1 + 1.0f), Cc));
        rs[1][j] += p1;
        plds[(16 + 4 * g + j) * 40 + 16 * c + r] = (_Float16)p1;
      }
    }
    // ---- P·V, accumulate into persistent C registers ----
    h8 a0 = *(const h8*)((unsigned char*)plds + r * 80 + 16 * g);
    h8 a1 = *(const h8*)((unsigned char*)plds + (16 + r) * 80 + 16 * g);
    __builtin_amdgcn_s_setprio(1);
#pragma unroll
    for (int cd = 0; cd < 8; ++cd) {
      const int d = 16 * cd + r;
      int byi = (d << 7) + ((64 * h + 16 * g) ^ (((d >> 1) & 7) << 4));
      h8 vf = *(const h8*)(smem + 16384 + byi);
      acc[0][cd] = MFMA16(a0, vf, acc[0][cd]);
      acc[1][cd] = MFMA16(a1, vf, acc[1][cd]);
    }
    __builtin_amdgcn_s_setprio(0);
    __syncthreads();
  }

  // ---- rowsum: reduce over the 16 column-lanes ----
#pragma unroll
  for (int rf = 0; rf < 2; ++rf)
#pragma unroll
    for (int j = 0; j < 4; ++j) {
      float v = rs[rf][j];
      v += __shfl_xor(v, 1);
      v += __shfl_xor(v, 2);
      v += __shfl_xor(v, 4);
      v += __shfl_xor(v, 8);
      rs[rf][j] = v;
    }

  // ---- combine the two key-halves, normalize, store ----
  float* olds = (float*)smem;
  float* rslds = (float*)(smem + 43008);
  if (h == 1) {
    float* my = olds + rw * 4096;
#pragma unroll
    for (int rf = 0; rf < 2; ++rf)
#pragma unroll
      for (int cd = 0; cd < 8; ++cd)
#pragma unroll
        for (int j = 0; j < 4; ++j)
          my[(16 * rf + 4 * g + j) * 128 + 16 * cd + r] = acc[rf][cd][j];
    if (r == 0) {
#pragma unroll
      for (int rf = 0; rf < 2; ++rf)
#pragma unroll
        for (int j = 0; j < 4; ++j)
          rslds[rw * 32 + 16 * rf + 4 * g + j] = rs[rf][j];
    }
  }
  __syncthreads();
  if (h == 0) {
    const float* ot = olds + rw * 4096;
    float* ob = out + ((size_t)b * MM + m0) * DD;
#pragma unroll
    for (int rf = 0; rf < 2; ++rf)
#pragma unroll
      for (int j = 0; j < 4; ++j) {
        const int rl = 16 * rf + 4 * g + j;
        const float tot = rs[rf][j] + rslds[rw * 32 + rl];
        const float inv = __builtin_amdgcn_rcpf(tot);
#pragma unroll
        for (int cd = 0; cd < 8; ++cd) {
          float v = acc[rf][cd][j] + ot[rl * 128 + 16 * cd + r];
          ob[rl * DD + 16 * cd + r] = v * inv;
        }
      }
  }
}

extern "C" void kernel_launch(void* const* d_in, const int* in_sizes, int n_in,
                              void* d_out, int out_size, void* d_ws, size_t ws_size,
                              hipStream_t stream) {
  const float* Q = (const float*)d_in[0];
  const float* K = (const float*)d_in[1];
  const float* V = (const float*)d_in[2];
  const void* mask = d_in[3];
  float* biasC = (float*)d_ws;  // 32768 floats
  float* out = (float*)d_out;
  prep_bias<<<dim3(128), dim3(256), 0, stream>>>(mask, biasC);
  attn_main<<<dim3(512), dim3(256), 0, stream>>>(Q, K, V, biasC, out);
}

// Round 4
// 86.023 us; speedup vs baseline: 1.3603x; 1.0971x over previous
//
#include <hip/hip_runtime.h>
#include <hip/hip_fp16.h>

typedef _Float16 h8 __attribute__((ext_vector_type(8)));
typedef _Float16 h4 __attribute__((ext_vector_type(4)));
typedef float f32x4 __attribute__((ext_vector_type(4)));

#define MFMA16(a, b, c) __builtin_amdgcn_mfma_f32_16x16x32_f16((a), (b), (c), 0, 0, 0)

static constexpr int MM = 2048, NN = 2048, DD = 128;
static constexpr int MT = 64, KT = 64, NT = NN / KT;  // 32 key tiles
static constexpr size_t KV_IMG = (size_t)16 * 32 * 16384;  // 8 MiB per tensor
static constexpr size_t WS_NEED = 2 * KV_IMG + 32768 * 4;

static constexpr float C1 = 0.25503487f;              // 2*log2(e)/sqrt(128)
static constexpr float C2 = 28.853900817779268f;      // 20*log2(e)
static constexpr float CVALID = 14.426950408889634f;  // 10*log2(e)
static constexpr float CMASK = -1.0e30f;

__device__ inline void glds16(const void* g, void* l) {
  __builtin_amdgcn_global_load_lds(
      (const __attribute__((address_space(1))) void*)g,
      (__attribute__((address_space(3))) void*)l, 16, 0, 0);
}

// ---------------- mask -> per-key bias constant (exp2 domain) ----------------
__global__ __launch_bounds__(256) void prep_bias(const void* __restrict__ mraw,
                                                 float* __restrict__ biasC) {
  const int tid = threadIdx.x;
  const unsigned int* mw = (const unsigned int*)mraw;
  const unsigned char* mb = (const unsigned char*)mraw;
  int okW = 1;  // word-typed (i32 0/1 or f32 0.0/1.0)
  for (int w = tid; w < 8192; w += 256) {
    unsigned int v = mw[w];
    okW &= (v == 0u || v == 1u || v == 0x3f800000u) ? 1 : 0;
  }
  __shared__ int sW;
  if (tid == 0) sW = 1;
  __syncthreads();
  if (!okW) atomicAnd(&sW, 0);
  __syncthreads();
  const int i = blockIdx.x * 256 + tid;  // grid covers 32768
  bool masked = sW ? (mw[i] != 0u) : (mb[i] != 0);
  biasC[i] = masked ? CMASK : CVALID;
}

// ---------------- pre-pass: K,V f32 -> fp16 LDS-image blocks ----------------
// Per (batch,tile): 16 KB block, byte-identical to the wanted LDS layout.
// K image: byte = key*256 + ((16*oct) ^ ((key&7)<<4)), oct = d/8.
// V image: byte = d*128 + 16*(koct ^ ((d>>1)&7)), koct = key/8 (transposed).
__global__ __launch_bounds__(256) void prep_kv(const float* __restrict__ K,
                                               const float* __restrict__ V,
                                               unsigned char* __restrict__ kimg,
                                               unsigned char* __restrict__ vimg) {
  const int id = blockIdx.x;
  const int bt = id & 511;
  const int tid = threadIdx.x;
  const float* src;
  if (id < 512) {  // ---- K ----
    src = K + (size_t)bt * KT * DD;
    unsigned char* dst = kimg + (size_t)bt * 16384;
#pragma unroll
    for (int it = 0; it < 4; ++it) {
      const int key = (tid >> 4) + 16 * it;
      const int o = tid & 15;
      f32x4 a = *(const f32x4*)(src + key * DD + 8 * o);
      f32x4 c = *(const f32x4*)(src + key * DD + 8 * o + 4);
      h8 hv;
#pragma unroll
      for (int j = 0; j < 4; ++j) {
        hv[j] = (_Float16)a[j];
        hv[j + 4] = (_Float16)c[j];
      }
      *(h8*)(dst + key * 256 + ((16 * o) ^ ((key & 7) << 4))) = hv;
    }
  } else {  // ---- V (transpose) ----
    src = V + (size_t)bt * KT * DD;
    unsigned char* dst = vimg + (size_t)bt * 16384;
    const int d = tid & 127;
    const int half = tid >> 7;
#pragma unroll
    for (int ki = 0; ki < 4; ++ki) {
      const int koct = half * 4 + ki;
      h8 w;
#pragma unroll
      for (int q = 0; q < 8; ++q)
        w[q] = (_Float16)src[(8 * koct + q) * DD + d];
      *(h8*)(dst + d * 128 + 16 * (koct ^ ((d >> 1) & 7))) = w;
    }
  }
}

// ---------------- fused attention (image-staged, double-buffered) ----------------
__global__ __launch_bounds__(256, 2) void attn_main(
    const float* __restrict__ Qg, const unsigned char* __restrict__ kimg,
    const unsigned char* __restrict__ vimg, const float* __restrict__ biasC,
    float* __restrict__ out) {
  __shared__ __align__(16) unsigned char smem[76032];
  // [0,32768)      buf0: K 16K + V^T 16K (fp16, swizzled images)
  // [32768,65536)  buf1
  // [65536,75776)  per-wave P [32 rows][40 f16] (stride 80B)
  // [75776,76032)  rowsum exchange (64 f32)
  // epilogue: [0,32768) reused for partial-O exchange
  const int tid = threadIdx.x;
  const int lane = tid & 63;
  const int wv = tid >> 6;
  const int r = lane & 15;   // A-row / D-col index
  const int g = lane >> 4;   // k-octet index
  const int rw = wv >> 1;    // row half
  const int h = wv & 1;      // key half
  const int b = blockIdx.x >> 5;
  const int mt = blockIdx.x & 31;
  const int m0 = mt * MT + rw * 32;

  // ---- Q fragments fp16 (registers, reused for all 32 K-tiles) ----
  h8 qh[2][4];
  {
    const float* qb = Qg + ((size_t)b * MM + m0) * DD;
#pragma unroll
    for (int rf = 0; rf < 2; ++rf) {
      const float* qr = qb + (16 * rf + r) * DD;
#pragma unroll
      for (int t = 0; t < 4; ++t) {
        f32x4 a = *(const f32x4*)(qr + 32 * t + 8 * g);
        f32x4 c = *(const f32x4*)(qr + 32 * t + 8 * g + 4);
        h8 hi;
#pragma unroll
        for (int j = 0; j < 4; ++j) {
          hi[j] = (_Float16)a[j];
          hi[j + 4] = (_Float16)c[j];
        }
        qh[rf][t] = hi;
      }
    }
  }

  f32x4 acc[2][8];
#pragma unroll
  for (int rf = 0; rf < 2; ++rf)
#pragma unroll
    for (int cd = 0; cd < 8; ++cd) acc[rf][cd] = (f32x4){0.f, 0.f, 0.f, 0.f};
  float rs[2][4] = {{0.f, 0.f, 0.f, 0.f}, {0.f, 0.f, 0.f, 0.f}};

  const unsigned char* kib = kimg + (size_t)b * 32 * 16384;
  const unsigned char* vib = vimg + (size_t)b * 32 * 16384;
  const float* cb = biasC + b * NN;
  _Float16* plds = (_Float16*)(smem + 65536 + wv * 2560);

  // ---- prologue: stage tile 0 into buf0 ----
#pragma unroll
  for (int i = 0; i < 4; ++i) {
    const int off = wv * 4096 + i * 1024;
    glds16(kib + off + lane * 16, smem + off);
    glds16(vib + off + lane * 16, smem + 16384 + off);
  }
  __syncthreads();  // drains vmcnt(0): tile 0 resident

  for (int tn = 0; tn < NT; ++tn) {
    const unsigned char* kbuf = smem + (tn & 1) * 32768;
    const unsigned char* vbuf = kbuf + 16384;
    // ---- issue next tile's global->LDS loads (fly during compute) ----
    if (tn + 1 < NT) {
      unsigned char* nbuf = smem + ((tn + 1) & 1) * 32768;
      const unsigned char* ks = kib + (size_t)(tn + 1) * 16384;
      const unsigned char* vs = vib + (size_t)(tn + 1) * 16384;
#pragma unroll
      for (int i = 0; i < 4; ++i) {
        const int off = wv * 4096 + i * 1024;
        glds16(ks + off + lane * 16, nbuf + off);
        glds16(vs + off + lane * 16, nbuf + 16384 + off);
      }
    }

    // ---- QK^T + clipped-softmax transform ----
#pragma unroll
    for (int c = 0; c < 2; ++c) {
      f32x4 S0 = {0.f, 0.f, 0.f, 0.f}, S1 = {0.f, 0.f, 0.f, 0.f};
      const int key = h * 32 + 16 * c + r;
      const int krow = key << 8;
      const int ksw = (key & 7) << 4;
      __builtin_amdgcn_s_setprio(1);
#pragma unroll
      for (int t = 0; t < 4; ++t) {
        h8 kf = *(const h8*)(kbuf + krow + ((64 * t + 16 * g) ^ ksw));
        S0 = MFMA16(qh[0][t], kf, S0);
        S1 = MFMA16(qh[1][t], kf, S1);
      }
      __builtin_amdgcn_s_setprio(0);
      const float Cc = cb[tn * KT + key];
#pragma unroll
      for (int j = 0; j < 4; ++j) {
        float u0 = __builtin_amdgcn_exp2f(S0[j] * C1);
        float p0 = __builtin_amdgcn_exp2f(
            fmaf(-C2, __builtin_amdgcn_rcpf(u0 + 1.0f), Cc));
        rs[0][j] += p0;
        plds[(4 * g + j) * 40 + 16 * c + r] = (_Float16)p0;
        float u1 = __builtin_amdgcn_exp2f(S1[j] * C1);
        float p1 = __builtin_amdgcn_exp2f(
            fmaf(-C2, __builtin_amdgcn_rcpf(u1 + 1.0f), Cc));
        rs[1][j] += p1;
        plds[(16 + 4 * g + j) * 40 + 16 * c + r] = (_Float16)p1;
      }
    }
    // ---- P·V, accumulate into persistent C registers ----
    h8 a0 = *(const h8*)((unsigned char*)plds + r * 80 + 16 * g);
    h8 a1 = *(const h8*)((unsigned char*)plds + (16 + r) * 80 + 16 * g);
    __builtin_amdgcn_s_setprio(1);
#pragma unroll
    for (int cd = 0; cd < 8; ++cd) {
      const int d = 16 * cd + r;
      h8 vf = *(const h8*)(vbuf + (d << 7) +
                           ((64 * h + 16 * g) ^ (((d >> 1) & 7) << 4)));
      acc[0][cd] = MFMA16(a0, vf, acc[0][cd]);
      acc[1][cd] = MFMA16(a1, vf, acc[1][cd]);
    }
    __builtin_amdgcn_s_setprio(0);
    __syncthreads();  // drains vmcnt: next tile resident, this buf read done
  }

  // ---- rowsum: reduce over the 16 column-lanes ----
#pragma unroll
  for (int rf = 0; rf < 2; ++rf)
#pragma unroll
    for (int j = 0; j < 4; ++j) {
      float v = rs[rf][j];
      v += __shfl_xor(v, 1);
      v += __shfl_xor(v, 2);
      v += __shfl_xor(v, 4);
      v += __shfl_xor(v, 8);
      rs[rf][j] = v;
    }

  // ---- combine the two key-halves, normalize, store ----
  float* olds = (float*)smem;
  float* rslds = (float*)(smem + 75776);
  if (h == 1) {
    float* my = olds + rw * 4096;
#pragma unroll
    for (int rf = 0; rf < 2; ++rf)
#pragma unroll
      for (int cd = 0; cd < 8; ++cd)
#pragma unroll
        for (int j = 0; j < 4; ++j)
          my[(16 * rf + 4 * g + j) * 128 + 16 * cd + r] = acc[rf][cd][j];
    if (r == 0) {
#pragma unroll
      for (int rf = 0; rf < 2; ++rf)
#pragma unroll
        for (int j = 0; j < 4; ++j)
          rslds[rw * 32 + 16 * rf + 4 * g + j] = rs[rf][j];
    }
  }
  __syncthreads();
  if (h == 0) {
    const float* ot = olds + rw * 4096;
    float* ob = out + ((size_t)b * MM + m0) * DD;
#pragma unroll
    for (int rf = 0; rf < 2; ++rf)
#pragma unroll
      for (int j = 0; j < 4; ++j) {
        const int rl = 16 * rf + 4 * g + j;
        const float tot = rs[rf][j] + rslds[rw * 32 + rl];
        const float inv = __builtin_amdgcn_rcpf(tot);
#pragma unroll
        for (int cd = 0; cd < 8; ++cd) {
          float v = acc[rf][cd][j] + ot[rl * 128 + 16 * cd + r];
          ob[rl * DD + 16 * cd + r] = v * inv;
        }
      }
  }
}

// ---------------- fallback (round-3 path) if ws too small ----------------
__global__ __launch_bounds__(256, 2) void attn_fallback(
    const float* __restrict__ Qg, const float* __restrict__ Kg,
    const float* __restrict__ Vg, const float* __restrict__ biasC,
    float* __restrict__ out) {
  __shared__ __align__(16) unsigned char smem[51456];
  const int tid = threadIdx.x;
  const int lane = tid & 63;
  const int wv = tid >> 6;
  const int r = lane & 15;
  const int g = lane >> 4;
  const int rw = wv >> 1;
  const int h = wv & 1;
  const int b = blockIdx.x >> 5;
  const int mt = blockIdx.x & 31;
  const int m0 = mt * MT + rw * 32;

  float* blds = (float*)(smem + 43264);
  {
    const float* cb = biasC + b * NN;
#pragma unroll
    for (int i = 0; i < 8; ++i) blds[tid + 256 * i] = cb[tid + 256 * i];
  }
  h8 qh[2][4];
  {
    const float* qb = Qg + ((size_t)b * MM + m0) * DD;
#pragma unroll
    for (int rf = 0; rf < 2; ++rf) {
      const float* qr = qb + (16 * rf + r) * DD;
#pragma unroll
      for (int t = 0; t < 4; ++t) {
        f32x4 a = *(const f32x4*)(qr + 32 * t + 8 * g);
        f32x4 c = *(const f32x4*)(qr + 32 * t + 8 * g + 4);
        h8 hi;
#pragma unroll
        for (int j = 0; j < 4; ++j) {
          hi[j] = (_Float16)a[j];
          hi[j + 4] = (_Float16)c[j];
        }
        qh[rf][t] = hi;
      }
    }
  }
  f32x4 acc[2][8];
#pragma unroll
  for (int rf = 0; rf < 2; ++rf)
#pragma unroll
    for (int cd = 0; cd < 8; ++cd) acc[rf][cd] = (f32x4){0.f, 0.f, 0.f, 0.f};
  float rs[2][4] = {{0.f, 0.f, 0.f, 0.f}, {0.f, 0.f, 0.f, 0.f}};
  const float* kb = Kg + (size_t)b * NN * DD;
  const float* vbp = Vg + (size_t)b * NN * DD;
  _Float16* plds = (_Float16*)(smem + 32768 + wv * 2560);
  const int bk0 = tid >> 5, bd0 = tid & 31;
  const int bk1 = (256 + tid) >> 5, bd1 = tid & 31;
  f32x4 kpre[8], vpre[8];
#pragma unroll
  for (int i = 0; i < 8; ++i) kpre[i] = *(const f32x4*)(kb + i * 1024 + tid * 4);
#pragma unroll
  for (int q = 0; q < 4; ++q) {
    vpre[q] = *(const f32x4*)(vbp + (4 * bk0 + q) * DD + 4 * bd0);
    vpre[4 + q] = *(const f32x4*)(vbp + (4 * bk1 + q) * DD + 4 * bd1);
  }
  for (int tn = 0; tn < NT; ++tn) {
#pragma unroll
    for (int i = 0; i < 8; ++i) {
      const int flat = i * 1024 + tid * 4;
      const int key = flat >> 7;
      const int d0 = flat & 127;
      h4 hv;
#pragma unroll
      for (int j = 0; j < 4; ++j) hv[j] = (_Float16)kpre[i][j];
      *(h4*)(smem + (key << 8) + ((d0 << 1) ^ ((key & 7) << 4))) = hv;
    }
#pragma unroll
    for (int it = 0; it < 2; ++it) {
      const int bk = it ? bk1 : bk0;
      const int bd = it ? bd1 : bd0;
#pragma unroll
      for (int p = 0; p < 4; ++p) {
        h4 w;
#pragma unroll
        for (int q = 0; q < 4; ++q) w[q] = (_Float16)vpre[it * 4 + q][p];
        const int d = 4 * bd + p;
        *(h4*)(smem + 16384 + (d << 7) +
               ((bk << 3) ^ (((d >> 1) & 7) << 4))) = w;
      }
    }
    if (tn + 1 < NT) {
      const float* ks = kb + (tn + 1) * KT * DD;
      const float* vs = vbp + (tn + 1) * KT * DD;
#pragma unroll
      for (int i = 0; i < 8; ++i) kpre[i] = *(const f32x4*)(ks + i * 1024 + tid * 4);
#pragma unroll
      for (int q = 0; q < 4; ++q) {
        vpre[q] = *(const f32x4*)(vs + (4 * bk0 + q) * DD + 4 * bd0);
        vpre[4 + q] = *(const f32x4*)(vs + (4 * bk1 + q) * DD + 4 * bd1);
      }
    }
    __syncthreads();
#pragma unroll
    for (int c = 0; c < 2; ++c) {
      f32x4 S0 = {0.f, 0.f, 0.f, 0.f}, S1 = {0.f, 0.f, 0.f, 0.f};
      const int key = h * 32 + 16 * c + r;
      const int krow = key << 8;
      const int ksw = (key & 7) << 4;
#pragma unroll
      for (int t = 0; t < 4; ++t) {
        h8 kf = *(const h8*)(smem + krow + ((64 * t + 16 * g) ^ ksw));
        S0 = MFMA16(qh[0][t], kf, S0);
        S1 = MFMA16(qh[1][t], kf, S1);
      }
      const float Cc = blds[tn * KT + key];
#pragma unroll
      for (int j = 0; j < 4; ++j) {
        float u0 = __builtin_amdgcn_exp2f(S0[j] * C1);
        float p0 = __builtin_amdgcn_exp2f(
            fmaf(-C2, __builtin_amdgcn_rcpf(u0 + 1.0f), Cc));
        rs[0][j] += p0;
        plds[(4 * g + j) * 40 + 16 * c + r] = (_Float16)p0;
        float u1 = __builtin_amdgcn_exp2f(S1[j] * C1);
        float p1 = __builtin_amdgcn_exp2f(
            fmaf(-C2, __builtin_amdgcn_rcpf(u1 + 1.0f), Cc));
        rs[1][j] += p1;
        plds[(16 + 4 * g + j) * 40 + 16 * c + r] = (_Float16)p1;
      }
    }
    h8 a0 = *(const h8*)((unsigned char*)plds + r * 80 + 16 * g);
    h8 a1 = *(const h8*)((unsigned char*)plds + (16 + r) * 80 + 16 * g);
#pragma unroll
    for (int cd = 0; cd < 8; ++cd) {
      const int d = 16 * cd + r;
      h8 vf = *(const h8*)(smem + 16384 + (d << 7) +
                           ((64 * h + 16 * g) ^ (((d >> 1) & 7) << 4)));
      acc[0][cd] = MFMA16(a0, vf, acc[0][cd]);
      acc[1][cd] = MFMA16(a1, vf, acc[1][cd]);
    }
    __syncthreads();
  }
#pragma unroll
  for (int rf = 0; rf < 2; ++rf)
#pragma unroll
    for (int j = 0; j < 4; ++j) {
      float v = rs[rf][j];
      v += __shfl_xor(v, 1);
      v += __shfl_xor(v, 2);
      v += __shfl_xor(v, 4);
      v += __shfl_xor(v, 8);
      rs[rf][j] = v;
    }
  float* olds = (float*)smem;
  float* rslds = (float*)(smem + 43008);
  if (h == 1) {
    float* my = olds + rw * 4096;
#pragma unroll
    for (int rf = 0; rf < 2; ++rf)
#pragma unroll
      for (int cd = 0; cd < 8; ++cd)
#pragma unroll
        for (int j = 0; j < 4; ++j)
          my[(16 * rf + 4 * g + j) * 128 + 16 * cd + r] = acc[rf][cd][j];
    if (r == 0) {
#pragma unroll
      for (int rf = 0; rf < 2; ++rf)
#pragma unroll
        for (int j = 0; j < 4; ++j)
          rslds[rw * 32 + 16 * rf + 4 * g + j] = rs[rf][j];
    }
  }
  __syncthreads();
  if (h == 0) {
    const float* ot = olds + rw * 4096;
    float* ob = out + ((size_t)b * MM + m0) * DD;
#pragma unroll
    for (int rf = 0; rf < 2; ++rf)
#pragma unroll
      for (int j = 0; j < 4; ++j) {
        const int rl = 16 * rf + 4 * g + j;
        const float tot = rs[rf][j] + rslds[rw * 32 + rl];
        const float inv = __builtin_amdgcn_rcpf(tot);
#pragma unroll
        for (int cd = 0; cd < 8; ++cd) {
          float v = acc[rf][cd][j] + ot[rl * 128 + 16 * cd + r];
          ob[rl * DD + 16 * cd + r] = v * inv;
        }
      }
  }
}

extern "C" void kernel_launch(void* const* d_in, const int* in_sizes, int n_in,
                              void* d_out, int out_size, void* d_ws, size_t ws_size,
                              hipStream_t stream) {
  const float* Q = (const float*)d_in[0];
  const float* K = (const float*)d_in[1];
  const float* V = (const float*)d_in[2];
  const void* mask = d_in[3];
  float* out = (float*)d_out;
  if (ws_size >= WS_NEED) {
    unsigned char* kimg = (unsigned char*)d_ws;
    unsigned char* vimg = kimg + KV_IMG;
    float* biasC = (float*)(kimg + 2 * KV_IMG);
    prep_bias<<<dim3(128), dim3(256), 0, stream>>>(mask, biasC);
    prep_kv<<<dim3(1024), dim3(256), 0, stream>>>(K, V, kimg, vimg);
    attn_main<<<dim3(512), dim3(256), 0, stream>>>(Q, kimg, vimg, biasC, out);
  } else {
    float* biasC = (float*)d_ws;  // 32768 floats
    prep_bias<<<dim3(128), dim3(256), 0, stream>>>(mask, biasC);
    attn_fallback<<<dim3(512), dim3(256), 0, stream>>>(Q, K, V, biasC, out);
  }
}

// Round 5
// 81.973 us; speedup vs baseline: 1.4275x; 1.0494x over previous
//
#include <hip/hip_runtime.h>
#include <hip/hip_fp16.h>

typedef _Float16 h8 __attribute__((ext_vector_type(8)));
typedef _Float16 h4 __attribute__((ext_vector_type(4)));
typedef float f32x4 __attribute__((ext_vector_type(4)));

#define MFMA16(a, b, c) __builtin_amdgcn_mfma_f32_16x16x32_f16((a), (b), (c), 0, 0, 0)

static constexpr int MM = 2048, NN = 2048, DD = 128;
static constexpr int MT = 64, KT = 64, NT = NN / KT;  // 32 key tiles
static constexpr size_t KV_IMG = (size_t)16 * 32 * 16384;  // 8 MiB per tensor
static constexpr size_t WS_NEED = 2 * KV_IMG + 32768 * 4;

static constexpr float C1 = 0.25503487f;              // 2*log2(e)/sqrt(128)
static constexpr float C2 = 28.853900817779268f;      // 20*log2(e)
static constexpr float CVALID = 14.426950408889634f;  // 10*log2(e)
static constexpr float CMASK = -1.0e30f;

__device__ inline void glds16(const void* g, void* l) {
  __builtin_amdgcn_global_load_lds(
      (const __attribute__((address_space(1))) void*)g,
      (__attribute__((address_space(3))) void*)l, 16, 0, 0);
}

// ---------------- fused pre-pass: K,V f32 -> fp16 LDS-images + mask bias ----
// K image: byte = key*256 + ((16*oct) ^ ((key&7)<<4)), oct = d/8.
// V image: byte = d*128 + 16*(koct ^ ((d>>1)&7)), koct = key/8 (transposed).
__global__ __launch_bounds__(256) void prep_all(
    const float* __restrict__ K, const float* __restrict__ V,
    const void* __restrict__ mraw, unsigned char* __restrict__ kimg,
    unsigned char* __restrict__ vimg, float* __restrict__ biasC) {
  const int id = blockIdx.x;
  const int tid = threadIdx.x;
  if (id >= 1024) {  // ---- mask -> bias (exp2 domain) ----
    const unsigned int* mw = (const unsigned int*)mraw;
    const unsigned char* mb = (const unsigned char*)mraw;
    int okW = 1;  // word-typed (i32 0/1 or f32 0.0/1.0)
    for (int w = tid; w < 8192; w += 256) {
      unsigned int v = mw[w];
      okW &= (v == 0u || v == 1u || v == 0x3f800000u) ? 1 : 0;
    }
    __shared__ int sW;
    if (tid == 0) sW = 1;
    __syncthreads();
    if (!okW) atomicAnd(&sW, 0);
    __syncthreads();
    const int i = (id - 1024) * 256 + tid;  // covers 32768
    bool masked = sW ? (mw[i] != 0u) : (mb[i] != 0);
    biasC[i] = masked ? CMASK : CVALID;
    return;
  }
  const int bt = id & 511;
  if (id < 512) {  // ---- K ----
    const float* src = K + (size_t)bt * KT * DD;
    unsigned char* dst = kimg + (size_t)bt * 16384;
#pragma unroll
    for (int it = 0; it < 4; ++it) {
      const int key = (tid >> 4) + 16 * it;
      const int o = tid & 15;
      f32x4 a = *(const f32x4*)(src + key * DD + 8 * o);
      f32x4 c = *(const f32x4*)(src + key * DD + 8 * o + 4);
      h8 hv;
#pragma unroll
      for (int j = 0; j < 4; ++j) {
        hv[j] = (_Float16)a[j];
        hv[j + 4] = (_Float16)c[j];
      }
      *(h8*)(dst + key * 256 + ((16 * o) ^ ((key & 7) << 4))) = hv;
    }
  } else {  // ---- V (transpose) ----
    const float* src = V + (size_t)bt * KT * DD;
    unsigned char* dst = vimg + (size_t)bt * 16384;
    const int d = tid & 127;
    const int half = tid >> 7;
#pragma unroll
    for (int ki = 0; ki < 4; ++ki) {
      const int koct = half * 4 + ki;
      h8 w;
#pragma unroll
      for (int q = 0; q < 8; ++q)
        w[q] = (_Float16)src[(8 * koct + q) * DD + d];
      *(h8*)(dst + d * 128 + 16 * (koct ^ ((d >> 1) & 7))) = w;
    }
  }
}

// ---------------- fused attention: 8 waves = 4 row-quarters x 2 key-halves ----
// Each wave: 16 q-rows x 32 keys per tile. 2 blocks/CU => 16 waves/CU.
// XCD-batch swizzle: XCD k handles batches {2k,2k+1} so its 2 MB of images
// stays L2-resident across the 32 M-tile re-reads.
__global__ __launch_bounds__(512, 4) void attn_main(
    const float* __restrict__ Qg, const unsigned char* __restrict__ kimg,
    const unsigned char* __restrict__ vimg, const float* __restrict__ biasC,
    float* __restrict__ out) {
  __shared__ __align__(16) unsigned char smem[76032];
  // [0,32768)      buf0: K 16K + V^T 16K (fp16, swizzled images)
  // [32768,65536)  buf1
  // [65536,75776)  per-wave P [16 rows][40 f16] (stride 80B) x 8 waves
  // [75776,76032)  rowsum exchange (64 f32)
  // epilogue: [0,32768) reused for partial-O exchange
  const int tid = threadIdx.x;
  const int lane = tid & 63;
  const int wv = tid >> 6;   // 0..7
  const int r = lane & 15;   // A-row / D-col index
  const int g = lane >> 4;   // k-octet index
  const int rw = wv >> 1;    // row quarter (16 rows)
  const int h = wv & 1;      // key half
  const int bid = blockIdx.x;
  const int swz = ((bid & 7) << 6) | (bid >> 3);  // XCD-batch locality
  const int b = swz >> 5;
  const int mt = swz & 31;
  const int m0 = mt * MT + rw * 16;

  // ---- Q fragments fp16 (registers, reused for all 32 K-tiles) ----
  h8 qh[4];
  {
    const float* qr = Qg + ((size_t)b * MM + m0 + r) * DD;
#pragma unroll
    for (int t = 0; t < 4; ++t) {
      f32x4 a = *(const f32x4*)(qr + 32 * t + 8 * g);
      f32x4 c = *(const f32x4*)(qr + 32 * t + 8 * g + 4);
      h8 hi;
#pragma unroll
      for (int j = 0; j < 4; ++j) {
        hi[j] = (_Float16)a[j];
        hi[j + 4] = (_Float16)c[j];
      }
      qh[t] = hi;
    }
  }

  f32x4 acc[8];
#pragma unroll
  for (int cd = 0; cd < 8; ++cd) acc[cd] = (f32x4){0.f, 0.f, 0.f, 0.f};
  float rs[4] = {0.f, 0.f, 0.f, 0.f};

  const unsigned char* kib = kimg + (size_t)b * 32 * 16384;
  const unsigned char* vib = vimg + (size_t)b * 32 * 16384;
  const float* cb = biasC + b * NN;
  _Float16* plds = (_Float16*)(smem + 65536 + wv * 1280);

  // ---- prologue: stage tile 0 into buf0 ----
#pragma unroll
  for (int i = 0; i < 2; ++i) {
    const int off = wv * 2048 + i * 1024;
    glds16(kib + off + lane * 16, smem + off);
    glds16(vib + off + lane * 16, smem + 16384 + off);
  }
  __syncthreads();  // drains vmcnt(0): tile 0 resident

  for (int tn = 0; tn < NT; ++tn) {
    const unsigned char* kbuf = smem + (tn & 1) * 32768;
    const unsigned char* vbuf = kbuf + 16384;
    // ---- issue next tile's global->LDS loads (fly during compute) ----
    if (tn + 1 < NT) {
      unsigned char* nbuf = smem + ((tn + 1) & 1) * 32768;
      const unsigned char* ks = kib + (size_t)(tn + 1) * 16384;
      const unsigned char* vs = vib + (size_t)(tn + 1) * 16384;
#pragma unroll
      for (int i = 0; i < 2; ++i) {
        const int off = wv * 2048 + i * 1024;
        glds16(ks + off + lane * 16, nbuf + off);
        glds16(vs + off + lane * 16, nbuf + 16384 + off);
      }
    }

    // ---- QK^T + clipped-softmax transform ----
#pragma unroll
    for (int c = 0; c < 2; ++c) {
      f32x4 S = {0.f, 0.f, 0.f, 0.f};
      const int key = h * 32 + 16 * c + r;
      const int krow = key << 8;
      const int ksw = (key & 7) << 4;
      __builtin_amdgcn_s_setprio(1);
#pragma unroll
      for (int t = 0; t < 4; ++t) {
        h8 kf = *(const h8*)(kbuf + krow + ((64 * t + 16 * g) ^ ksw));
        S = MFMA16(qh[t], kf, S);
      }
      __builtin_amdgcn_s_setprio(0);
      const float Cc = cb[tn * KT + key];
#pragma unroll
      for (int j = 0; j < 4; ++j) {
        float u = __builtin_amdgcn_exp2f(S[j] * C1);
        float p = __builtin_amdgcn_exp2f(
            fmaf(-C2, __builtin_amdgcn_rcpf(u + 1.0f), Cc));
        rs[j] += p;
        plds[(4 * g + j) * 40 + 16 * c + r] = (_Float16)p;
      }
    }
    // ---- P·V, accumulate into persistent C registers ----
    h8 a0 = *(const h8*)((unsigned char*)plds + r * 80 + 16 * g);
    __builtin_amdgcn_s_setprio(1);
#pragma unroll
    for (int cd = 0; cd < 8; ++cd) {
      const int d = 16 * cd + r;
      h8 vf = *(const h8*)(vbuf + (d << 7) +
                           ((64 * h + 16 * g) ^ (((d >> 1) & 7) << 4)));
      acc[cd] = MFMA16(a0, vf, acc[cd]);
    }
    __builtin_amdgcn_s_setprio(0);
    __syncthreads();  // next tile resident; this buf free for overwrite
  }

  // ---- rowsum: reduce over the 16 column-lanes ----
#pragma unroll
  for (int j = 0; j < 4; ++j) {
    float v = rs[j];
    v += __shfl_xor(v, 1);
    v += __shfl_xor(v, 2);
    v += __shfl_xor(v, 4);
    v += __shfl_xor(v, 8);
    rs[j] = v;
  }

  // ---- combine the two key-halves, normalize, store ----
  float* olds = (float*)smem;
  float* rslds = (float*)(smem + 75776);
  if (h == 1) {
    float* my = olds + rw * 2048;
#pragma unroll
    for (int cd = 0; cd < 8; ++cd)
#pragma unroll
      for (int j = 0; j < 4; ++j)
        my[(4 * g + j) * 128 + 16 * cd + r] = acc[cd][j];
    if (r == 0) {
#pragma unroll
      for (int j = 0; j < 4; ++j) rslds[rw * 16 + 4 * g + j] = rs[j];
    }
  }
  __syncthreads();
  if (h == 0) {
    const float* ot = olds + rw * 2048;
    float* ob = out + ((size_t)b * MM + m0) * DD;
#pragma unroll
    for (int j = 0; j < 4; ++j) {
      const int rl = 4 * g + j;
      const float tot = rs[j] + rslds[rw * 16 + rl];
      const float inv = __builtin_amdgcn_rcpf(tot);
#pragma unroll
      for (int cd = 0; cd < 8; ++cd) {
        float v = acc[cd][j] + ot[rl * 128 + 16 * cd + r];
        ob[rl * DD + 16 * cd + r] = v * inv;
      }
    }
  }
}

// ---------------- fallback (round-3 path) if ws too small ----------------
__global__ __launch_bounds__(256, 2) void attn_fallback(
    const float* __restrict__ Qg, const float* __restrict__ Kg,
    const float* __restrict__ Vg, const float* __restrict__ biasC,
    float* __restrict__ out) {
  __shared__ __align__(16) unsigned char smem[51456];
  const int tid = threadIdx.x;
  const int lane = tid & 63;
  const int wv = tid >> 6;
  const int r = lane & 15;
  const int g = lane >> 4;
  const int rw = wv >> 1;
  const int h = wv & 1;
  const int b = blockIdx.x >> 5;
  const int mt = blockIdx.x & 31;
  const int m0 = mt * MT + rw * 32;

  float* blds = (float*)(smem + 43264);
  {
    const float* cb = biasC + b * NN;
#pragma unroll
    for (int i = 0; i < 8; ++i) blds[tid + 256 * i] = cb[tid + 256 * i];
  }
  h8 qh[2][4];
  {
    const float* qb = Qg + ((size_t)b * MM + m0) * DD;
#pragma unroll
    for (int rf = 0; rf < 2; ++rf) {
      const float* qr = qb + (16 * rf + r) * DD;
#pragma unroll
      for (int t = 0; t < 4; ++t) {
        f32x4 a = *(const f32x4*)(qr + 32 * t + 8 * g);
        f32x4 c = *(const f32x4*)(qr + 32 * t + 8 * g + 4);
        h8 hi;
#pragma unroll
        for (int j = 0; j < 4; ++j) {
          hi[j] = (_Float16)a[j];
          hi[j + 4] = (_Float16)c[j];
        }
        qh[rf][t] = hi;
      }
    }
  }
  f32x4 acc[2][8];
#pragma unroll
  for (int rf = 0; rf < 2; ++rf)
#pragma unroll
    for (int cd = 0; cd < 8; ++cd) acc[rf][cd] = (f32x4){0.f, 0.f, 0.f, 0.f};
  float rs[2][4] = {{0.f, 0.f, 0.f, 0.f}, {0.f, 0.f, 0.f, 0.f}};
  const float* kb = Kg + (size_t)b * NN * DD;
  const float* vbp = Vg + (size_t)b * NN * DD;
  _Float16* plds = (_Float16*)(smem + 32768 + wv * 2560);
  const int bk0 = tid >> 5, bd0 = tid & 31;
  const int bk1 = (256 + tid) >> 5, bd1 = tid & 31;
  f32x4 kpre[8], vpre[8];
#pragma unroll
  for (int i = 0; i < 8; ++i) kpre[i] = *(const f32x4*)(kb + i * 1024 + tid * 4);
#pragma unroll
  for (int q = 0; q < 4; ++q) {
    vpre[q] = *(const f32x4*)(vbp + (4 * bk0 + q) * DD + 4 * bd0);
    vpre[4 + q] = *(const f32x4*)(vbp + (4 * bk1 + q) * DD + 4 * bd1);
  }
  for (int tn = 0; tn < NT; ++tn) {
#pragma unroll
    for (int i = 0; i < 8; ++i) {
      const int flat = i * 1024 + tid * 4;
      const int key = flat >> 7;
      const int d0 = flat & 127;
      h4 hv;
#pragma unroll
      for (int j = 0; j < 4; ++j) hv[j] = (_Float16)kpre[i][j];
      *(h4*)(smem + (key << 8) + ((d0 << 1) ^ ((key & 7) << 4))) = hv;
    }
#pragma unroll
    for (int it = 0; it < 2; ++it) {
      const int bk = it ? bk1 : bk0;
      const int bd = it ? bd1 : bd0;
#pragma unroll
      for (int p = 0; p < 4; ++p) {
        h4 w;
#pragma unroll
        for (int q = 0; q < 4; ++q) w[q] = (_Float16)vpre[it * 4 + q][p];
        const int d = 4 * bd + p;
        *(h4*)(smem + 16384 + (d << 7) +
               ((bk << 3) ^ (((d >> 1) & 7) << 4))) = w;
      }
    }
    if (tn + 1 < NT) {
      const float* ks = kb + (tn + 1) * KT * DD;
      const float* vs = vbp + (tn + 1) * KT * DD;
#pragma unroll
      for (int i = 0; i < 8; ++i) kpre[i] = *(const f32x4*)(ks + i * 1024 + tid * 4);
#pragma unroll
      for (int q = 0; q < 4; ++q) {
        vpre[q] = *(const f32x4*)(vs + (4 * bk0 + q) * DD + 4 * bd0);
        vpre[4 + q] = *(const f32x4*)(vs + (4 * bk1 + q) * DD + 4 * bd1);
      }
    }
    __syncthreads();
#pragma unroll
    for (int c = 0; c < 2; ++c) {
      f32x4 S0 = {0.f, 0.f, 0.f, 0.f}, S1 = {0.f, 0.f, 0.f, 0.f};
      const int key = h * 32 + 16 * c + r;
      const int krow = key << 8;
      const int ksw = (key & 7) << 4;
#pragma unroll
      for (int t = 0; t < 4; ++t) {
        h8 kf = *(const h8*)(smem + krow + ((64 * t + 16 * g) ^ ksw));
        S0 = MFMA16(qh[0][t], kf, S0);
        S1 = MFMA16(qh[1][t], kf, S1);
      }
      const float Cc = blds[tn * KT + key];
#pragma unroll
      for (int j = 0; j < 4; ++j) {
        float u0 = __builtin_amdgcn_exp2f(S0[j] * C1);
        float p0 = __builtin_amdgcn_exp2f(
            fmaf(-C2, __builtin_amdgcn_rcpf(u0 + 1.0f), Cc));
        rs[0][j] += p0;
        plds[(4 * g + j) * 40 + 16 * c + r] = (_Float16)p0;
        float u1 = __builtin_amdgcn_exp2f(S1[j] * C1);
        float p1 = __builtin_amdgcn_exp2f(
            fmaf(-C2, __builtin_amdgcn_rcpf(u1 + 1.0f), Cc));
        rs[1][j] += p1;
        plds[(16 + 4 * g + j) * 40 + 16 * c + r] = (_Float16)p1;
      }
    }
    h8 a0 = *(const h8*)((unsigned char*)plds + r * 80 + 16 * g);
    h8 a1 = *(const h8*)((unsigned char*)plds + (16 + r) * 80 + 16 * g);
#pragma unroll
    for (int cd = 0; cd < 8; ++cd) {
      const int d = 16 * cd + r;
      h8 vf = *(const h8*)(smem + 16384 + (d << 7) +
                           ((64 * h + 16 * g) ^ (((d >> 1) & 7) << 4)));
      acc[0][cd] = MFMA16(a0, vf, acc[0][cd]);
      acc[1][cd] = MFMA16(a1, vf, acc[1][cd]);
    }
    __syncthreads();
  }
#pragma unroll
  for (int rf = 0; rf < 2; ++rf)
#pragma unroll
    for (int j = 0; j < 4; ++j) {
      float v = rs[rf][j];
      v += __shfl_xor(v, 1);
      v += __shfl_xor(v, 2);
      v += __shfl_xor(v, 4);
      v += __shfl_xor(v, 8);
      rs[rf][j] = v;
    }
  float* olds = (float*)smem;
  float* rslds = (float*)(smem + 43008);
  if (h == 1) {
    float* my = olds + rw * 4096;
#pragma unroll
    for (int rf = 0; rf < 2; ++rf)
#pragma unroll
      for (int cd = 0; cd < 8; ++cd)
#pragma unroll
        for (int j = 0; j < 4; ++j)
          my[(16 * rf + 4 * g + j) * 128 + 16 * cd + r] = acc[rf][cd][j];
    if (r == 0) {
#pragma unroll
      for (int rf = 0; rf < 2; ++rf)
#pragma unroll
        for (int j = 0; j < 4; ++j)
          rslds[rw * 32 + 16 * rf + 4 * g + j] = rs[rf][j];
    }
  }
  __syncthreads();
  if (h == 0) {
    const float* ot = olds + rw * 4096;
    float* ob = out + ((size_t)b * MM + m0) * DD;
#pragma unroll
    for (int rf = 0; rf < 2; ++rf)
#pragma unroll
      for (int j = 0; j < 4; ++j) {
        const int rl = 16 * rf + 4 * g + j;
        const float tot = rs[rf][j] + rslds[rw * 32 + rl];
        const float inv = __builtin_amdgcn_rcpf(tot);
#pragma unroll
        for (int cd = 0; cd < 8; ++cd) {
          float v = acc[rf][cd][j] + ot[rl * 128 + 16 * cd + r];
          ob[rl * DD + 16 * cd + r] = v * inv;
        }
      }
  }
}

extern "C" void kernel_launch(void* const* d_in, const int* in_sizes, int n_in,
                              void* d_out, int out_size, void* d_ws, size_t ws_size,
                              hipStream_t stream) {
  const float* Q = (const float*)d_in[0];
  const float* K = (const float*)d_in[1];
  const float* V = (const float*)d_in[2];
  const void* mask = d_in[3];
  float* out = (float*)d_out;
  if (ws_size >= WS_NEED) {
    unsigned char* kimg = (unsigned char*)d_ws;
    unsigned char* vimg = kimg + KV_IMG;
    float* biasC = (float*)(kimg + 2 * KV_IMG);
    prep_all<<<dim3(1152), dim3(256), 0, stream>>>(K, V, mask, kimg, vimg, biasC);
    attn_main<<<dim3(512), dim3(512), 0, stream>>>(Q, kimg, vimg, biasC, out);
  } else {
    float* biasC = (float*)d_ws;  // 32768 floats
    // inline bias prep via prep_all's bias blocks only is not separable;
    // use a tiny grid of prep_all bias blocks:
    prep_all<<<dim3(1152), dim3(256), 0, stream>>>(K, V, mask,
        (unsigned char*)d_ws, (unsigned char*)d_ws, biasC);  // unreachable path
    attn_fallback<<<dim3(512), dim3(256), 0, stream>>>(Q, K, V, biasC, out);
  }
}